// Round 2
// baseline (182.647 us; speedup 1.0000x reference)
//
#include <hip/hip_runtime.h>

// ---------------------------------------------------------------------------
// MaskedMultiHeadAttention: B=2, T=2048, E=1024, H=16, D=64, WINDOW=256
//
// R13: T3+T4 GEMM — 3-stage software pipeline with COUNTED vmcnt waits and
// raw s_barrier (no vmcnt(0) drain in the main loop). 512-thread / 8-wave
// blocks so 3 LDS stages fit at full SIMD occupancy:
//   QKV:  <128,192,64>, 120KB LDS, grid 16x32 (2 rounds of 1 block/CU)
//   proj: <128,128,64>,  96KB LDS, grid  8x32 (1 round,  1 block/CU)
// Per iteration: wait vmcnt(LDW) [stage(it) landed, stage(it+1) still
// flying] -> lgkmcnt(0) [prev compute's ds_reads done before overwrite]
// -> s_barrier -> issue stage(it+2) -> MFMA on stage(it).
// Prologue and attention unchanged from R11/R12.
// ---------------------------------------------------------------------------

typedef __bf16 bf16_t;
typedef bf16_t bf16x8 __attribute__((ext_vector_type(8)));
typedef bf16_t bf16x4 __attribute__((ext_vector_type(4)));
typedef float  floatx4 __attribute__((ext_vector_type(4)));

#define SEQ_T   2048
#define NHEAD   16
#define HDIM    64
#define EMB     1024
#define WIN     256
#define SCALE_F 0.125f

template<int N> __device__ __forceinline__ void waitcnt_vm()
{
    if constexpr (N == 0)      asm volatile("s_waitcnt vmcnt(0)" ::: "memory");
    else if constexpr (N == 4) asm volatile("s_waitcnt vmcnt(4)" ::: "memory");
    else if constexpr (N == 5) asm volatile("s_waitcnt vmcnt(5)" ::: "memory");
    else static_assert(N == 0 || N == 4 || N == 5, "add vmcnt literal");
}

// ---------------------------------------------------------------------------
// Wave-uniform dtype detect: all waves read the same 1 KB of hidden.
// ---------------------------------------------------------------------------
__device__ __forceinline__ int detect_bf16(const uint4* __restrict__ det)
{
    const int lane = threadIdx.x & 63;
    const uint4 v = det[lane];
    int c = 0;
    #pragma unroll
    for (int e = 0; e < 4; ++e) {
        const unsigned int ex = ((&v.x)[e] >> 7) & 0xffu;
        c += (ex >= 100u && ex <= 150u) ? 1 : 0;
    }
    #pragma unroll
    for (int m = 32; m >= 1; m >>= 1) c += __shfl_xor(c, m, 64);
    return (c * 2 > 256) ? 1 : 0;
}

// ---------------------------------------------------------------------------
// Fused prologue (one launch): canon (fp32 mode only) + both transposes.
// ---------------------------------------------------------------------------
__global__ __launch_bounds__(256) void prologue(
    const void* __restrict__ hidden, bf16_t* __restrict__ Hc,
    const void* __restrict__ ba, bf16_t* __restrict__ bba,
    const void* __restrict__ bp, bf16_t* __restrict__ bbp,
    const void* __restrict__ wA, bf16_t* __restrict__ WtA,
    const void* __restrict__ wP, bf16_t* __restrict__ WtP)
{
    __shared__ __align__(16) bf16_t tile[64][68];
    const int f = detect_bf16((const uint4*)hidden);
    const int blk = blockIdx.x;

    if (blk < 4100) {                       // canonicalize path
        if (f) return;
        const float* src;
        bf16_t* dst;
        int base;
        if (blk < 4096)      { src = (const float*)hidden; dst = Hc;  base = blk * 1024; }
        else if (blk < 4099) { src = (const float*)ba;     dst = bba; base = (blk - 4096) * 1024; }
        else                 { src = (const float*)bp;     dst = bbp; base = 0; }
        const int i4 = base + threadIdx.x * 4;
        const float4 x = *(const float4*)(src + i4);
        bf16x4 v;
        v[0] = (bf16_t)x.x; v[1] = (bf16_t)x.y;
        v[2] = (bf16_t)x.z; v[3] = (bf16_t)x.w;
        *(bf16x4*)(dst + i4) = v;
        return;
    }

    int id = blk - 4100;
    const void* W; bf16_t* Wt; int N, bx, by;
    if (id < 768) { W = wA; Wt = WtA; N = 3072; bx = id % 48; by = id / 48; }
    else { id -= 768; W = wP; Wt = WtP; N = 1024; bx = id % 16; by = id / 16; }
    const int K = 1024;
    const int n0 = bx * 64;
    const int k0 = by * 64;
    const int tx = threadIdx.x & 15;
    const int ty = threadIdx.x >> 4;

    #pragma unroll
    for (int r = ty; r < 64; r += 16) {
        bf16x4 v;
        const size_t base = (size_t)(k0 + r) * N + n0 + tx * 4;
        if (f) {
            v = *(const bf16x4*)((const bf16_t*)W + base);
        } else {
            const float4 x = *(const float4*)((const float*)W + base);
            v[0] = (bf16_t)x.x; v[1] = (bf16_t)x.y;
            v[2] = (bf16_t)x.z; v[3] = (bf16_t)x.w;
        }
        *(bf16x4*)&tile[r][tx * 4] = v;
    }
    __syncthreads();
    #pragma unroll
    for (int r = ty; r < 64; r += 16) {
        bf16x4 v;
        v[0] = tile[tx * 4 + 0][r];
        v[1] = tile[tx * 4 + 1][r];
        v[2] = tile[tx * 4 + 2][r];
        v[3] = tile[tx * 4 + 3][r];
        *(bf16x4*)(Wt + (size_t)(n0 + r) * K + k0 + tx * 4) = v;
    }
}

// ---------------------------------------------------------------------------
// C[M][N] = A[M][K] @ Bt[N][K]^T + bias[N]   (bf16 in, fp32 accumulate)
// R13: 8-wave (512t) block, 3-stage pipeline, counted vmcnt, raw s_barrier.
// XOR source-address swizzle unchanged (stored slot s of row r holds global
// chunk s ^ (r & CM); LDS dest stays wave-uniform + lane*16) -> conflict-free
// fragment reads.
// ---------------------------------------------------------------------------
template<int BMt, int BNt, int BKt>
__global__ __launch_bounds__(512, 2) void gemm_bt_bias(
    const bf16_t* __restrict__ Abf,   // used when flag==1 (bf16 input)
    const bf16_t* __restrict__ Aalt,  // used when flag==0 (canonicalized)
    const bf16_t* __restrict__ Bt,
    const bf16_t* __restrict__ biasbf,
    const bf16_t* __restrict__ biasalt,
    void* __restrict__ C,
    int M, int N, int K,
    int force_bf16, const uint4* __restrict__ det)
{
    constexpr int NF  = BNt / 64;     // n-frags per wave (wave tile 64 x BNt/4)
    constexpr int LPR = BKt / 8;      // 16B chunks (lanes) per row
    constexpr int CM  = LPR - 1;      // chunk/swizzle mask
    constexpr int RPL = 64 / LPR;     // rows per global_load_lds
    constexpr int SL  = BKt / 32;     // K-slices per tile
    constexpr int LA  = (BMt / 8) / RPL;  // A-loads per wave per stage
    constexpr int LB  = (BNt / 8) / RPL;  // B-loads per wave per stage
    constexpr int LDW = LA + LB;          // loads in flight per stage per wave
    __shared__ __align__(16) bf16_t As[3][BMt * BKt];
    __shared__ __align__(16) bf16_t Bs[3][BNt * BKt];

    const int flag = detect_bf16(det);
    const bf16_t* A    = flag ? Abf    : Aalt;
    const bf16_t* bias = flag ? biasbf : biasalt;
    const int obf = force_bf16 | flag;

    const int tid  = threadIdx.x;
    const int wave = tid >> 6;        // 0..7
    const int lane = tid & 63;
    const int quad = lane >> 4;
    const int n16  = lane & 15;
    const int m0 = blockIdx.y * BMt;
    const int n0 = blockIdx.x * BNt;
    const int wm = (wave >> 2) * 64;          // 2 waves in M
    const int wn = (wave & 3) * (BNt / 4);    // 4 waves in N

    floatx4 acc[4][NF] = {};

    const int lr   = lane / LPR;      // local row within a load
    const int lc16 = lane % LPR;      // stored chunk slot

    auto stage = [&](int bsel, int k0) {
        #pragma unroll
        for (int t = 0; t < LA; ++t) {
            const int row0 = wave * (BMt / 8) + t * RPL;
            const int g = (lc16 ^ ((row0 + lr) & CM)) * 8;
            const bf16_t* ga = A + (size_t)(m0 + row0 + lr) * K + k0 + g;
            __builtin_amdgcn_global_load_lds(
                (const __attribute__((address_space(1))) void*)ga,
                (__attribute__((address_space(3))) void*)(As[bsel] + row0 * BKt),
                16, 0, 0);
        }
        #pragma unroll
        for (int t = 0; t < LB; ++t) {
            const int row0 = wave * (BNt / 8) + t * RPL;
            const int g = (lc16 ^ ((row0 + lr) & CM)) * 8;
            const bf16_t* gb = Bt + (size_t)(n0 + row0 + lr) * K + k0 + g;
            __builtin_amdgcn_global_load_lds(
                (const __attribute__((address_space(1))) void*)gb,
                (__attribute__((address_space(3))) void*)(Bs[bsel] + row0 * BKt),
                16, 0, 0);
        }
    };

    stage(0, 0);
    stage(1, BKt);

    const int NIT = K / BKt;
    int cur = 0;
    for (int it = 0; it < NIT; ++it) {
        // stage(it) must have landed (keep stage(it+1)'s LDW loads in flight)
        if (it + 1 < NIT) waitcnt_vm<LDW>();
        else              waitcnt_vm<0>();
        // prev iteration's ds_reads complete before stage(it+2) overwrites
        asm volatile("s_waitcnt lgkmcnt(0)" ::: "memory");
        __builtin_amdgcn_s_barrier();

        if (it + 2 < NIT) {
            int nb = cur + 2; if (nb >= 3) nb -= 3;
            stage(nb, (it + 2) * BKt);
        }

        const bf16_t* __restrict__ Ab = As[cur];
        const bf16_t* __restrict__ Bb = Bs[cur];
        // fragment rows: row&CM == n16&CM; want global chunk (4s+quad)
        #pragma unroll
        for (int s = 0; s < SL; ++s) {
            const int ch = (((4 * s + quad) ^ (n16 & CM)) * 8);
            const bf16_t* pa = Ab + (wm + n16) * BKt + ch;
            const bf16_t* pb = Bb + (wn + n16) * BKt + ch;
            bf16x8 af[4], bfr[NF];
            #pragma unroll
            for (int ff = 0; ff < 4; ++ff)
                af[ff] = *(const bf16x8*)(pa + ff * 16 * BKt);
            #pragma unroll
            for (int ff = 0; ff < NF; ++ff)
                bfr[ff] = *(const bf16x8*)(pb + ff * 16 * BKt);
            #pragma unroll
            for (int mf = 0; mf < 4; ++mf)
                #pragma unroll
                for (int nf = 0; nf < NF; ++nf)
                    acc[mf][nf] = __builtin_amdgcn_mfma_f32_16x16x32_bf16(
                        af[mf], bfr[nf], acc[mf][nf], 0, 0, 0);
        }
        cur += 1; if (cur >= 3) cur -= 3;
    }

    const int col   = n0 + wn + n16;
    const int rbase = m0 + wm + quad * 4;
    #pragma unroll
    for (int nf = 0; nf < NF; ++nf) {
        const float bv = (float)bias[col + nf * 16];
        #pragma unroll
        for (int mf = 0; mf < 4; ++mf) {
            #pragma unroll
            for (int r = 0; r < 4; ++r) {
                const size_t idx =
                    (size_t)(rbase + mf * 16 + r) * N + col + nf * 16;
                const float val = acc[mf][nf][r] + bv;
                if (obf) ((bf16_t*)C)[idx] = (bf16_t)val;
                else     ((float*)C)[idx]  = val;
            }
        }
    }
}

// ---------------------------------------------------------------------------
// MFMA flash attention (R10): 4 chunks of 80 keys, 36KB LDS, 4 blocks/CU,
// V-reg and K-lds prefetch hidden under compute. PV pads cols 80..95 = 0.
// ---------------------------------------------------------------------------
#define CW   80
#define NCH  4
#define VT_S 104
#define P_S  104

__global__ __launch_bounds__(256) void attn_mfma(
    const bf16_t* __restrict__ qkv,
    bf16_t* __restrict__ attn_out)
{
    __shared__ __align__(16) bf16_t Ks[CW * 64];       // 10240 B
    __shared__ __align__(16) bf16_t Vt[64 * VT_S];     // 13312 B
    __shared__ __align__(16) bf16_t Pst[4][16 * P_S];  // 13312 B

    const int tid  = threadIdx.x;
    const int wave = tid >> 6;
    const int lane = tid & 63;
    const int quad = lane >> 4;
    const int n16  = lane & 15;

    const int i0 = blockIdx.x * 64;
    const int h  = blockIdx.y;
    const int b  = blockIdx.z;
    const size_t rowbase = (size_t)b * SEQ_T;
    const int kbase  = i0 - 256;
    const int iw     = 16 * wave;
    const int climit = 256 - i0;

    const bf16_t* Qg = qkv + (rowbase + i0 + iw + n16) * (3 * EMB) + h * HDIM;
    bf16x8 qf[2];
    qf[0] = *(const bf16x8*)(Qg + quad * 8);
    qf[1] = *(const bf16x8*)(Qg + 32 + quad * 8);

    for (int i = tid; i < 1024; i += 256)
        Vt[(i >> 4) * VT_S + 80 + (i & 15)] = (bf16_t)0.f;
    for (int i = tid; i < 1024; i += 256)
        Pst[i >> 8][((i >> 4) & 15) * P_S + 80 + (i & 15)] = (bf16_t)0.f;

    floatx4 Oac[4] = {};
    float m_run[4], l_run[4];
    #pragma unroll
    for (int rr = 0; rr < 4; ++rr) { m_run[rr] = -3.0e38f; l_run[rr] = 0.f; }

    bf16x8 vreg[3];

    auto loadV = [&](int hc) {
        const int cbase = hc * CW;
        #pragma unroll
        for (int t = 0; t < 3; ++t) {
            const int idx = tid + 256 * t;
            if (idx < 640) {
                const int lc = idx >> 3;
                const int d0 = (idx & 7) * 8;
                int j = kbase + cbase + lc; if (j < 0) j = 0;
                vreg[t] = *(const bf16x8*)(qkv + (rowbase + j) * (3 * EMB)
                                           + 2 * EMB + h * HDIM + d0);
            }
        }
    };
    auto stageK = [&](int hc) {
        const int cbase = hc * CW;
        for (int t = wave; t < 10; t += 4) {
            const int lc0 = t * 8;
            const int lcL = lc0 + (lane >> 3);
            int j = kbase + cbase + lcL; if (j < 0) j = 0;
            const int g = (lane & 7) ^ (lane >> 3);
            const bf16_t* src = qkv + (rowbase + j) * (3 * EMB)
                                + EMB + h * HDIM + g * 8;
            __builtin_amdgcn_global_load_lds(
                (const __attribute__((address_space(1))) void*)src,
                (__attribute__((address_space(3))) void*)(Ks + lc0 * 64),
                16, 0, 0);
        }
    };
    auto writeVt = [&]() {
        #pragma unroll
        for (int t = 0; t < 3; ++t) {
            const int idx = tid + 256 * t;
            if (idx < 640) {
                const int lc = idx >> 3;
                const int d0 = (idx & 7) * 8;
                #pragma unroll
                for (int e = 0; e < 8; ++e)
                    Vt[(d0 + e) * VT_S + lc] = vreg[t][e];
            }
        }
    };

    loadV(0);
    stageK(0);

    for (int hc = 0; hc < NCH; ++hc) {
        const int cbase = hc * CW;

        __syncthreads();   // A: K(hc) staged; prev PV done (Vt/Pst free)
        writeVt();
        __syncthreads();   // B: Vt visible

        if (hc < NCH - 1) loadV(hc + 1);   // flies during QK/softmax

        floatx4 sc[5];
        #pragma unroll
        for (int tt = 0; tt < 5; ++tt) {
            sc[tt] = (floatx4){0.f, 0.f, 0.f, 0.f};
            #pragma unroll
            for (int s2 = 0; s2 < 2; ++s2) {
                const int lc = 16 * tt + n16;
                const int ch = (4 * s2 + quad) ^ (lc & 7);
                const bf16x8 kf = *(const bf16x8*)(Ks + lc * 64 + ch * 8);
                sc[tt] = __builtin_amdgcn_mfma_f32_16x16x32_bf16(
                    qf[s2], kf, sc[tt], 0, 0, 0);
            }
        }

        #pragma unroll
        for (int tt = 0; tt < 5; ++tt) {
            const int c  = cbase + 16 * tt + n16;
            const int cw = c - iw;
            #pragma unroll
            for (int rr = 0; rr < 4; ++rr) {
                const int r = quad * 4 + rr;
                const bool valid = (cw > r) && (cw <= r + 256) && (c >= climit);
                sc[tt][rr] = valid ? sc[tt][rr] * SCALE_F : -3.0e38f;
            }
        }

        float cm[4];
        #pragma unroll
        for (int rr = 0; rr < 4; ++rr) {
            cm[rr] = -3.0e38f;
            #pragma unroll
            for (int tt = 0; tt < 5; ++tt) cm[rr] = fmaxf(cm[rr], sc[tt][rr]);
            #pragma unroll
            for (int m = 8; m >= 1; m >>= 1)
                cm[rr] = fmaxf(cm[rr], __shfl_xor(cm[rr], m, 64));
        }
        #pragma unroll
        for (int rr = 0; rr < 4; ++rr) {
            const float mnew  = fmaxf(m_run[rr], cm[rr]);
            const float alpha = __expf(m_run[rr] - mnew);
            m_run[rr] = mnew;
            l_run[rr] *= alpha;
            #pragma unroll
            for (int nt = 0; nt < 4; ++nt) Oac[nt][rr] *= alpha;
        }

        float psum[4] = {0.f, 0.f, 0.f, 0.f};
        #pragma unroll
        for (int tt = 0; tt < 5; ++tt) {
            #pragma unroll
            for (int rr = 0; rr < 4; ++rr) {
                const float s = sc[tt][rr];
                const float e = (s > -1.0e38f) ? __expf(s - m_run[rr]) : 0.f;
                psum[rr] += e;
                Pst[wave][(quad * 4 + rr) * P_S + 16 * tt + n16] = (bf16_t)e;
            }
        }
        #pragma unroll
        for (int rr = 0; rr < 4; ++rr) {
            #pragma unroll
            for (int m = 8; m >= 1; m >>= 1)
                psum[rr] += __shfl_xor(psum[rr], m, 64);
            l_run[rr] += psum[rr];
        }

        __syncthreads();   // C: Pst visible; QK done reading Ks

        if (hc < NCH - 1) stageK(hc + 1);  // flies during PV

        #pragma unroll
        for (int ks = 0; ks < 3; ++ks) {
            const bf16x8 paf = *(const bf16x8*)(
                &Pst[wave][n16 * P_S + ks * 32 + quad * 8]);
            #pragma unroll
            for (int nt = 0; nt < 4; ++nt) {
                const bf16x8 vbf = *(const bf16x8*)(
                    Vt + (nt * 16 + n16) * VT_S + ks * 32 + quad * 8);
                Oac[nt] = __builtin_amdgcn_mfma_f32_16x16x32_bf16(
                    paf, vbf, Oac[nt], 0, 0, 0);
            }
        }
    }

    #pragma unroll
    for (int rr = 0; rr < 4; ++rr) {
        const float rden = 1.0f / l_run[rr];
        const size_t row = rowbase + i0 + iw + quad * 4 + rr;
        #pragma unroll
        for (int nt = 0; nt < 4; ++nt) {
            attn_out[row * EMB + h * HDIM + nt * 16 + n16] =
                (bf16_t)(Oac[nt][rr] * rden);
        }
    }
}

// ---------------------------------------------------------------------------
extern "C" void kernel_launch(void* const* d_in, const int* in_sizes, int n_in,
                              void* d_out, int out_size, void* d_ws, size_t ws_size,
                              hipStream_t stream)
{
    const void* hidden = d_in[0];
    const void* w_attn = d_in[1];
    const void* b_attn = d_in[2];
    const void* w_proj = d_in[3];
    const void* b_proj = d_in[4];

    char* ws = (char*)d_ws;
    bf16_t* Wt_attn = (bf16_t*)(ws);                       // [3072][1024]
    bf16_t* Wt_proj = (bf16_t*)(ws + (6u << 20));          // [1024][1024]
    bf16_t* qkv     = (bf16_t*)(ws + (8u << 20));          // [4096][3072]
    bf16_t* attn_o  = (bf16_t*)(ws + (32u << 20));         // [4096][1024]
    bf16_t* Hc      = (bf16_t*)(ws + (40u << 20));         // [4096][1024]
    bf16_t* bb_attn = (bf16_t*)(ws + (48u << 20));
    bf16_t* bb_proj = (bf16_t*)(ws + (48u << 20) + 8192);

    const uint4* det = (const uint4*)hidden;

    prologue<<<5124, 256, 0, stream>>>(hidden, Hc, b_attn, bb_attn,
                                       b_proj, bb_proj,
                                       w_attn, Wt_attn, w_proj, Wt_proj);

    gemm_bt_bias<128, 192, 64><<<dim3(3072 / 192, 4096 / 128), 512, 0, stream>>>(
        (const bf16_t*)hidden, Hc, Wt_attn,
        (const bf16_t*)b_attn, bb_attn, qkv, 4096, 3072, 1024, 1, det);

    attn_mfma<<<dim3(SEQ_T / 64, NHEAD, 2), 256, 0, stream>>>(qkv, attn_o);

    gemm_bt_bias<128, 128, 64><<<dim3(1024 / 128, 4096 / 128), 512, 0, stream>>>(
        attn_o, attn_o, Wt_proj,
        (const bf16_t*)b_proj, bb_proj, (void*)d_out, 4096, 1024, 1024, 0, det);
}

// Round 3
// 160.750 us; speedup vs baseline: 1.1362x; 1.1362x over previous
//
#include <hip/hip_runtime.h>

// ---------------------------------------------------------------------------
// MaskedMultiHeadAttention: B=2, T=2048, E=1024, H=16, D=64, WINDOW=256
//
// R14: GEMMs reverted to R11 (best measured: QKV <192,64> 2 blk/CU,
// proj <64,128>). Attention: Vt re-laid-out as [64][128] with 16B-chunk
// XOR swizzle  c' = c ^ ((d ^ (d>>3)) & 7)  applied identically on
// writeVt / PV-read / zero-pad. Kills writeVt's 16-way bank conflict
// (64 lanes -> 4 banks, since 8*row_stride = 0 mod 32 words) down to
// 2-way (free). T5 s_setprio(1) wrapped around QK and PV MFMA clusters
// (attn-confirmed +4-7%, m191). LDS 39936 B -> still 4 blocks/CU.
// ---------------------------------------------------------------------------

typedef __bf16 bf16_t;
typedef bf16_t bf16x8 __attribute__((ext_vector_type(8)));
typedef bf16_t bf16x4 __attribute__((ext_vector_type(4)));
typedef float  floatx4 __attribute__((ext_vector_type(4)));

#define SEQ_T   2048
#define NHEAD   16
#define HDIM    64
#define EMB     1024
#define WIN     256
#define SCALE_F 0.125f

// ---------------------------------------------------------------------------
// Wave-uniform dtype detect: all waves read the same 1 KB of hidden.
// ---------------------------------------------------------------------------
__device__ __forceinline__ int detect_bf16(const uint4* __restrict__ det)
{
    const int lane = threadIdx.x & 63;
    const uint4 v = det[lane];
    int c = 0;
    #pragma unroll
    for (int e = 0; e < 4; ++e) {
        const unsigned int ex = ((&v.x)[e] >> 7) & 0xffu;
        c += (ex >= 100u && ex <= 150u) ? 1 : 0;
    }
    #pragma unroll
    for (int m = 32; m >= 1; m >>= 1) c += __shfl_xor(c, m, 64);
    return (c * 2 > 256) ? 1 : 0;
}

// ---------------------------------------------------------------------------
// Fused prologue (one launch): canon (fp32 mode only) + both transposes.
// ---------------------------------------------------------------------------
__global__ __launch_bounds__(256) void prologue(
    const void* __restrict__ hidden, bf16_t* __restrict__ Hc,
    const void* __restrict__ ba, bf16_t* __restrict__ bba,
    const void* __restrict__ bp, bf16_t* __restrict__ bbp,
    const void* __restrict__ wA, bf16_t* __restrict__ WtA,
    const void* __restrict__ wP, bf16_t* __restrict__ WtP)
{
    __shared__ __align__(16) bf16_t tile[64][68];
    const int f = detect_bf16((const uint4*)hidden);
    const int blk = blockIdx.x;

    if (blk < 4100) {                       // canonicalize path
        if (f) return;
        const float* src;
        bf16_t* dst;
        int base;
        if (blk < 4096)      { src = (const float*)hidden; dst = Hc;  base = blk * 1024; }
        else if (blk < 4099) { src = (const float*)ba;     dst = bba; base = (blk - 4096) * 1024; }
        else                 { src = (const float*)bp;     dst = bbp; base = 0; }
        const int i4 = base + threadIdx.x * 4;
        const float4 x = *(const float4*)(src + i4);
        bf16x4 v;
        v[0] = (bf16_t)x.x; v[1] = (bf16_t)x.y;
        v[2] = (bf16_t)x.z; v[3] = (bf16_t)x.w;
        *(bf16x4*)(dst + i4) = v;
        return;
    }

    int id = blk - 4100;
    const void* W; bf16_t* Wt; int N, bx, by;
    if (id < 768) { W = wA; Wt = WtA; N = 3072; bx = id % 48; by = id / 48; }
    else { id -= 768; W = wP; Wt = WtP; N = 1024; bx = id % 16; by = id / 16; }
    const int K = 1024;
    const int n0 = bx * 64;
    const int k0 = by * 64;
    const int tx = threadIdx.x & 15;
    const int ty = threadIdx.x >> 4;

    #pragma unroll
    for (int r = ty; r < 64; r += 16) {
        bf16x4 v;
        const size_t base = (size_t)(k0 + r) * N + n0 + tx * 4;
        if (f) {
            v = *(const bf16x4*)((const bf16_t*)W + base);
        } else {
            const float4 x = *(const float4*)((const float*)W + base);
            v[0] = (bf16_t)x.x; v[1] = (bf16_t)x.y;
            v[2] = (bf16_t)x.z; v[3] = (bf16_t)x.w;
        }
        *(bf16x4*)&tile[r][tx * 4] = v;
    }
    __syncthreads();
    #pragma unroll
    for (int r = ty; r < 64; r += 16) {
        bf16x4 v;
        v[0] = tile[tx * 4 + 0][r];
        v[1] = tile[tx * 4 + 1][r];
        v[2] = tile[tx * 4 + 2][r];
        v[3] = tile[tx * 4 + 3][r];
        *(bf16x4*)(Wt + (size_t)(n0 + r) * K + k0 + tx * 4) = v;
    }
}

// ---------------------------------------------------------------------------
// C[M][N] = A[M][K] @ Bt[N][K]^T + bias[N]   (bf16 in, fp32 accumulate)
// R11 structure (reverted): single-buffer global_load_lds + XOR source-addr
// swizzle; 2 blocks/CU for cross-block overlap. QKV: <192,64>; proj <64,128>.
// ---------------------------------------------------------------------------
template<int BNt, int BKt>
__global__ __launch_bounds__(256, 2) void gemm_bt_bias(
    const bf16_t* __restrict__ Abf,   // used when flag==1 (bf16 input)
    const bf16_t* __restrict__ Aalt,  // used when flag==0 (canonicalized)
    const bf16_t* __restrict__ Bt,
    const bf16_t* __restrict__ biasbf,
    const bf16_t* __restrict__ biasalt,
    void* __restrict__ C,
    int M, int N, int K,
    int force_bf16, const uint4* __restrict__ det)
{
    constexpr int BMt = 128;
    constexpr int NF  = BNt / 32;     // n-frags per wave (wave tile 64 x BNt/2)
    constexpr int LPR = BKt / 8;      // 16B chunks (lanes) per row
    constexpr int CM  = LPR - 1;      // chunk/swizzle mask
    constexpr int RPL = 64 / LPR;     // rows per global_load_lds
    constexpr int SL  = BKt / 32;     // K-slices per tile
    __shared__ __align__(16) bf16_t As[BMt * BKt];
    __shared__ __align__(16) bf16_t Bs[BNt * BKt];

    const int flag = detect_bf16(det);
    const bf16_t* A    = flag ? Abf    : Aalt;
    const bf16_t* bias = flag ? biasbf : biasalt;
    const int obf = force_bf16 | flag;

    const int tid  = threadIdx.x;
    const int wave = tid >> 6;
    const int lane = tid & 63;
    const int quad = lane >> 4;
    const int n16  = lane & 15;
    const int m0 = blockIdx.y * BMt;
    const int n0 = blockIdx.x * BNt;
    const int wm = (wave >> 1) * 64;
    const int wn = (wave & 1) * (BNt / 2);

    floatx4 acc[4][NF] = {};

    const int lr   = lane / LPR;      // local row within a load
    const int lc16 = lane % LPR;      // stored chunk slot

    for (int k0 = 0; k0 < K; k0 += BKt) {
        #pragma unroll
        for (int t = 0; t < (BMt / 4) / RPL; ++t) {
            const int row0 = wave * (BMt / 4) + t * RPL;
            const int g = (lc16 ^ ((row0 + lr) & CM)) * 8;
            const bf16_t* ga = A + (size_t)(m0 + row0 + lr) * K + k0 + g;
            __builtin_amdgcn_global_load_lds(
                (const __attribute__((address_space(1))) void*)ga,
                (__attribute__((address_space(3))) void*)(As + row0 * BKt),
                16, 0, 0);
        }
        #pragma unroll
        for (int t = 0; t < (BNt / 4) / RPL; ++t) {
            const int row0 = wave * (BNt / 4) + t * RPL;
            const int g = (lc16 ^ ((row0 + lr) & CM)) * 8;
            const bf16_t* gb = Bt + (size_t)(n0 + row0 + lr) * K + k0 + g;
            __builtin_amdgcn_global_load_lds(
                (const __attribute__((address_space(1))) void*)gb,
                (__attribute__((address_space(3))) void*)(Bs + row0 * BKt),
                16, 0, 0);
        }
        __syncthreads();

        // fragment rows: row&CM == n16&CM; want global chunk (4s+quad)
        #pragma unroll
        for (int s = 0; s < SL; ++s) {
            const int ch = (((4 * s + quad) ^ (n16 & CM)) * 8);
            const bf16_t* pa = As + (wm + n16) * BKt + ch;
            const bf16_t* pb = Bs + (wn + n16) * BKt + ch;
            bf16x8 af[4], bfr[NF];
            #pragma unroll
            for (int ff = 0; ff < 4; ++ff)
                af[ff] = *(const bf16x8*)(pa + ff * 16 * BKt);
            #pragma unroll
            for (int ff = 0; ff < NF; ++ff)
                bfr[ff] = *(const bf16x8*)(pb + ff * 16 * BKt);
            #pragma unroll
            for (int mf = 0; mf < 4; ++mf)
                #pragma unroll
                for (int nf = 0; nf < NF; ++nf)
                    acc[mf][nf] = __builtin_amdgcn_mfma_f32_16x16x32_bf16(
                        af[mf], bfr[nf], acc[mf][nf], 0, 0, 0);
        }
        __syncthreads();
    }

    const int col   = n0 + wn + n16;
    const int rbase = m0 + wm + quad * 4;
    #pragma unroll
    for (int nf = 0; nf < NF; ++nf) {
        const float bv = (float)bias[col + nf * 16];
        #pragma unroll
        for (int mf = 0; mf < 4; ++mf) {
            #pragma unroll
            for (int r = 0; r < 4; ++r) {
                const size_t idx =
                    (size_t)(rbase + mf * 16 + r) * N + col + nf * 16;
                const float val = acc[mf][nf][r] + bv;
                if (obf) ((bf16_t*)C)[idx] = (bf16_t)val;
                else     ((float*)C)[idx]  = val;
            }
        }
    }
}

// ---------------------------------------------------------------------------
// MFMA flash attention (R14): 4 chunks of 80 keys, 4 blocks/CU.
// Vt: [64 d][128 k] with 16B-chunk XOR swizzle  c' = c ^ ((d^(d>>3))&7).
// writeVt 16-way bank conflict -> 2-way; PV reads use same salt.
// s_setprio(1) around QK and PV MFMA clusters (T5).
// ---------------------------------------------------------------------------
#define CW   80
#define NCH  4
#define VT_S 128
#define P_S  104

__device__ __forceinline__ int vt_salt(int d) { return (d ^ (d >> 3)) & 7; }

__global__ __launch_bounds__(256) void attn_mfma(
    const bf16_t* __restrict__ qkv,
    bf16_t* __restrict__ attn_out)
{
    __shared__ __align__(16) bf16_t Ks[CW * 64];       // 10240 B
    __shared__ __align__(16) bf16_t Vt[64 * VT_S];     // 16384 B
    __shared__ __align__(16) bf16_t Pst[4][16 * P_S];  // 13312 B

    const int tid  = threadIdx.x;
    const int wave = tid >> 6;
    const int lane = tid & 63;
    const int quad = lane >> 4;
    const int n16  = lane & 15;

    const int i0 = blockIdx.x * 64;
    const int h  = blockIdx.y;
    const int b  = blockIdx.z;
    const size_t rowbase = (size_t)b * SEQ_T;
    const int kbase  = i0 - 256;
    const int iw     = 16 * wave;
    const int climit = 256 - i0;

    const bf16_t* Qg = qkv + (rowbase + i0 + iw + n16) * (3 * EMB) + h * HDIM;
    bf16x8 qf[2];
    qf[0] = *(const bf16x8*)(Qg + quad * 8);
    qf[1] = *(const bf16x8*)(Qg + 32 + quad * 8);

    // zero-pad k = 80..95 (chunks 10,11) at swizzled positions
    for (int i = tid; i < 1024; i += 256) {
        const int d = i >> 4;
        const int k = 80 + (i & 15);
        Vt[d * VT_S + (((k >> 3) ^ vt_salt(d)) << 3) + (k & 7)] = (bf16_t)0.f;
    }
    for (int i = tid; i < 1024; i += 256)
        Pst[i >> 8][((i >> 4) & 15) * P_S + 80 + (i & 15)] = (bf16_t)0.f;

    floatx4 Oac[4] = {};
    float m_run[4], l_run[4];
    #pragma unroll
    for (int rr = 0; rr < 4; ++rr) { m_run[rr] = -3.0e38f; l_run[rr] = 0.f; }

    bf16x8 vreg[3];

    auto loadV = [&](int hc) {
        const int cbase = hc * CW;
        #pragma unroll
        for (int t = 0; t < 3; ++t) {
            const int idx = tid + 256 * t;
            if (idx < 640) {
                const int lc = idx >> 3;
                const int d0 = (idx & 7) * 8;
                int j = kbase + cbase + lc; if (j < 0) j = 0;
                vreg[t] = *(const bf16x8*)(qkv + (rowbase + j) * (3 * EMB)
                                           + 2 * EMB + h * HDIM + d0);
            }
        }
    };
    auto stageK = [&](int hc) {
        const int cbase = hc * CW;
        for (int t = wave; t < 10; t += 4) {
            const int lc0 = t * 8;
            const int lcL = lc0 + (lane >> 3);
            int j = kbase + cbase + lcL; if (j < 0) j = 0;
            const int g = (lane & 7) ^ (lane >> 3);
            const bf16_t* src = qkv + (rowbase + j) * (3 * EMB)
                                + EMB + h * HDIM + g * 8;
            __builtin_amdgcn_global_load_lds(
                (const __attribute__((address_space(1))) void*)src,
                (__attribute__((address_space(3))) void*)(Ks + lc0 * 64),
                16, 0, 0);
        }
    };
    auto writeVt = [&]() {
        #pragma unroll
        for (int t = 0; t < 3; ++t) {
            const int idx = tid + 256 * t;
            if (idx < 640) {
                const int lc = idx >> 3;          // k index
                const int d0 = (idx & 7) * 8;     // d base
                #pragma unroll
                for (int e = 0; e < 8; ++e) {
                    const int d = d0 + e;
                    Vt[d * VT_S + (((lc >> 3) ^ vt_salt(d)) << 3) + (lc & 7)]
                        = vreg[t][e];
                }
            }
        }
    };

    loadV(0);
    stageK(0);

    for (int hc = 0; hc < NCH; ++hc) {
        const int cbase = hc * CW;

        __syncthreads();   // A: K(hc) staged; prev PV done (Vt/Pst free)
        writeVt();
        __syncthreads();   // B: Vt visible

        if (hc < NCH - 1) loadV(hc + 1);   // flies during QK/softmax

        floatx4 sc[5];
        __builtin_amdgcn_s_setprio(1);
        #pragma unroll
        for (int tt = 0; tt < 5; ++tt) {
            sc[tt] = (floatx4){0.f, 0.f, 0.f, 0.f};
            #pragma unroll
            for (int s2 = 0; s2 < 2; ++s2) {
                const int lc = 16 * tt + n16;
                const int ch = (4 * s2 + quad) ^ (lc & 7);
                const bf16x8 kf = *(const bf16x8*)(Ks + lc * 64 + ch * 8);
                sc[tt] = __builtin_amdgcn_mfma_f32_16x16x32_bf16(
                    qf[s2], kf, sc[tt], 0, 0, 0);
            }
        }
        __builtin_amdgcn_s_setprio(0);

        #pragma unroll
        for (int tt = 0; tt < 5; ++tt) {
            const int c  = cbase + 16 * tt + n16;
            const int cw = c - iw;
            #pragma unroll
            for (int rr = 0; rr < 4; ++rr) {
                const int r = quad * 4 + rr;
                const bool valid = (cw > r) && (cw <= r + 256) && (c >= climit);
                sc[tt][rr] = valid ? sc[tt][rr] * SCALE_F : -3.0e38f;
            }
        }

        float cm[4];
        #pragma unroll
        for (int rr = 0; rr < 4; ++rr) {
            cm[rr] = -3.0e38f;
            #pragma unroll
            for (int tt = 0; tt < 5; ++tt) cm[rr] = fmaxf(cm[rr], sc[tt][rr]);
            #pragma unroll
            for (int m = 8; m >= 1; m >>= 1)
                cm[rr] = fmaxf(cm[rr], __shfl_xor(cm[rr], m, 64));
        }
        #pragma unroll
        for (int rr = 0; rr < 4; ++rr) {
            const float mnew  = fmaxf(m_run[rr], cm[rr]);
            const float alpha = __expf(m_run[rr] - mnew);
            m_run[rr] = mnew;
            l_run[rr] *= alpha;
            #pragma unroll
            for (int nt = 0; nt < 4; ++nt) Oac[nt][rr] *= alpha;
        }

        float psum[4] = {0.f, 0.f, 0.f, 0.f};
        #pragma unroll
        for (int tt = 0; tt < 5; ++tt) {
            #pragma unroll
            for (int rr = 0; rr < 4; ++rr) {
                const float s = sc[tt][rr];
                const float e = (s > -1.0e38f) ? __expf(s - m_run[rr]) : 0.f;
                psum[rr] += e;
                Pst[wave][(quad * 4 + rr) * P_S + 16 * tt + n16] = (bf16_t)e;
            }
        }
        #pragma unroll
        for (int rr = 0; rr < 4; ++rr) {
            #pragma unroll
            for (int m = 8; m >= 1; m >>= 1)
                psum[rr] += __shfl_xor(psum[rr], m, 64);
            l_run[rr] += psum[rr];
        }

        __syncthreads();   // C: Pst visible; QK done reading Ks

        if (hc < NCH - 1) stageK(hc + 1);  // flies during PV

        __builtin_amdgcn_s_setprio(1);
        #pragma unroll
        for (int ks = 0; ks < 3; ++ks) {
            const bf16x8 paf = *(const bf16x8*)(
                &Pst[wave][n16 * P_S + ks * 32 + quad * 8]);
            #pragma unroll
            for (int nt = 0; nt < 4; ++nt) {
                const int d = nt * 16 + n16;
                const int cc = (ks * 4 + quad) ^ vt_salt(d);
                const bf16x8 vbf = *(const bf16x8*)(Vt + d * VT_S + cc * 8);
                Oac[nt] = __builtin_amdgcn_mfma_f32_16x16x32_bf16(
                    paf, vbf, Oac[nt], 0, 0, 0);
            }
        }
        __builtin_amdgcn_s_setprio(0);
    }

    #pragma unroll
    for (int rr = 0; rr < 4; ++rr) {
        const float rden = 1.0f / l_run[rr];
        const size_t row = rowbase + i0 + iw + quad * 4 + rr;
        #pragma unroll
        for (int nt = 0; nt < 4; ++nt) {
            attn_out[row * EMB + h * HDIM + nt * 16 + n16] =
                (bf16_t)(Oac[nt][rr] * rden);
        }
    }
}

// ---------------------------------------------------------------------------
extern "C" void kernel_launch(void* const* d_in, const int* in_sizes, int n_in,
                              void* d_out, int out_size, void* d_ws, size_t ws_size,
                              hipStream_t stream)
{
    const void* hidden = d_in[0];
    const void* w_attn = d_in[1];
    const void* b_attn = d_in[2];
    const void* w_proj = d_in[3];
    const void* b_proj = d_in[4];

    char* ws = (char*)d_ws;
    bf16_t* Wt_attn = (bf16_t*)(ws);                       // [3072][1024]
    bf16_t* Wt_proj = (bf16_t*)(ws + (6u << 20));          // [1024][1024]
    bf16_t* qkv     = (bf16_t*)(ws + (8u << 20));          // [4096][3072]
    bf16_t* attn_o  = (bf16_t*)(ws + (32u << 20));         // [4096][1024]
    bf16_t* Hc      = (bf16_t*)(ws + (40u << 20));         // [4096][1024]
    bf16_t* bb_attn = (bf16_t*)(ws + (48u << 20));
    bf16_t* bb_proj = (bf16_t*)(ws + (48u << 20) + 8192);

    const uint4* det = (const uint4*)hidden;

    prologue<<<5124, 256, 0, stream>>>(hidden, Hc, b_attn, bb_attn,
                                       b_proj, bb_proj,
                                       w_attn, Wt_attn, w_proj, Wt_proj);

    gemm_bt_bias<192, 64><<<dim3(3072 / 192, 4096 / 128), 256, 0, stream>>>(
        (const bf16_t*)hidden, Hc, Wt_attn,
        (const bf16_t*)b_attn, bb_attn, qkv, 4096, 3072, 1024, 1, det);

    attn_mfma<<<dim3(SEQ_T / 64, NHEAD, 2), 256, 0, stream>>>(qkv, attn_o);

    gemm_bt_bias<64, 128><<<dim3(1024 / 64, 4096 / 128), 256, 0, stream>>>(
        attn_o, attn_o, Wt_proj,
        (const bf16_t*)b_proj, bb_proj, (void*)d_out, 4096, 1024, 1024, 0, det);
}